// Round 7
// baseline (143.196 us; speedup 1.0000x reference)
//
#include <hip/hip_runtime.h>

#define NBLOCKS 2048
#define NTHREADS 256
#define VPT 8                // float4s per array per thread
#define STEP 4               // float4s per array per pipeline step
#define OUTER (VPT / STEP)   // 2 steps
#define NXCD 8
#define NUM_LEVELS 101

typedef float f32x4 __attribute__((ext_vector_type(4)));

// Pass-through pin (NO memory clobber): forces the s_waitcnt for these values
// here while later independent nt-loads hoist above -> rolling counted-vmcnt
// pipeline that the scheduler does not collapse (rounds 4/6 verified).
#define PIN4(v) asm volatile("" : "+v"((v)[0]), "+v"((v)[1]), "+v"((v)[2]), "+v"((v)[3]))

#define GATHER_ACC(yv, xv)                                   \
    do {                                                     \
        float w0 = s_wt[__float2int_rn((yv)[0] * 100.f)];    \
        float w1 = s_wt[__float2int_rn((yv)[1] * 100.f)];    \
        float w2 = s_wt[__float2int_rn((yv)[2] * 100.f)];    \
        float w3 = s_wt[__float2int_rn((yv)[3] * 100.f)];    \
        float d0 = (xv)[0] - (yv)[0], d1 = (xv)[1] - (yv)[1];\
        float d2 = (xv)[2] - (yv)[2], d3 = (xv)[3] - (yv)[3];\
        a0 += d0 * d0 * w0 + d2 * d2 * w2;                   \
        a1 += d1 * d1 * w1 + d3 * d3 * w3;                   \
    } while (0)

// Stage 1: weighted-SSE partial sums, one float per block (plain store).
// nt loads (round 5: removed the L3 pacer, kernel now HBM-read-bound at
// ~3.8 TB/s). This round: XCD-affinity block swizzle (each XCD streams one
// contiguous 16-MB region per array instead of round-robin interleave) +
// 8-load pipeline steps. Both target read SERVICE rate -- concurrency is
// already oversubscribed per Little's law.
__global__ __launch_bounds__(NTHREADS) void wmse_partial(
    const float* __restrict__ x,
    const float* __restrict__ y,
    const float* __restrict__ wt,
    float* __restrict__ partial, int n)
{
    __shared__ float s_wt[NUM_LEVELS];
    __shared__ float s_red[NTHREADS / 64];

    const f32x4* __restrict__ x4 = (const f32x4*)x;
    const f32x4* __restrict__ y4 = (const f32x4*)y;
    const int n4 = n >> 2;

    float acc = 0.f;

    if (n4 == NBLOCKS * NTHREADS * VPT) {
        if (threadIdx.x < NUM_LEVELS) s_wt[threadIdx.x] = wt[threadIdx.x];
        __syncthreads();

        // XCD-affinity swizzle (bijective: NBLOCKS % NXCD == 0).
        // Blocks resident on XCD k (blockIdx.x % 8 == k) cover the k-th
        // contiguous 16-MB slice of each array.
        const int bid = (blockIdx.x % NXCD) * (NBLOCKS / NXCD) + blockIdx.x / NXCD;
        const int i0 = bid * (NTHREADS * VPT) + threadIdx.x;

        // preload step 0: 8 nt loads (128 B/lane in flight)
        f32x4 yc[STEP], xc[STEP];
        #pragma unroll
        for (int j = 0; j < STEP; ++j) {
            yc[j] = __builtin_nontemporal_load(y4 + i0 + j * NTHREADS);
            xc[j] = __builtin_nontemporal_load(x4 + i0 + j * NTHREADS);
        }

        float a0 = 0.f, a1 = 0.f;
        #pragma unroll
        for (int k = 0; k < OUTER; ++k) {
            f32x4 yn[STEP], xn[STEP];
            if (k < OUTER - 1) {
                #pragma unroll
                for (int j = 0; j < STEP; ++j) {
                    yn[j] = __builtin_nontemporal_load(y4 + i0 + ((k + 1) * STEP + j) * NTHREADS);
                    xn[j] = __builtin_nontemporal_load(x4 + i0 + ((k + 1) * STEP + j) * NTHREADS);
                }
            }
            // waits for CURRENT land here; next-step loads stay in flight
            #pragma unroll
            for (int j = 0; j < STEP; ++j) {
                PIN4(yc[j]); PIN4(xc[j]);
                GATHER_ACC(yc[j], xc[j]);
            }
            if (k < OUTER - 1) {
                #pragma unroll
                for (int j = 0; j < STEP; ++j) { yc[j] = yn[j]; xc[j] = xn[j]; }
            }
        }
        acc = a0 + a1;
    } else {
        // Generic fallback path (grid-stride, normal loads).
        for (int i = threadIdx.x; i < NUM_LEVELS; i += NTHREADS) s_wt[i] = wt[i];
        __syncthreads();
        const int stride = NBLOCKS * NTHREADS;
        float a0 = 0.f, a1 = 0.f;
        for (int i = blockIdx.x * NTHREADS + threadIdx.x; i < n4; i += stride) {
            f32x4 xv = x4[i], yv = y4[i];
            GATHER_ACC(yv, xv);
        }
        acc = a0 + a1;
    }

    // wave-64 shuffle reduction
    #pragma unroll
    for (int off = 32; off > 0; off >>= 1)
        acc += __shfl_down(acc, off, 64);

    const int lane = threadIdx.x & 63;
    const int wave = threadIdx.x >> 6;
    if (lane == 0) s_red[wave] = acc;
    __syncthreads();
    if (threadIdx.x == 0) {
        float s = 0.f;
        #pragma unroll
        for (int w = 0; w < NTHREADS / 64; ++w) s += s_red[w];
        partial[blockIdx.x] = s;   // plain store, no atomic
    }
}

// Stage 2: one block folds the partials and writes the final mean.
// Overwrites the poisoned output directly -> no memset node needed.
__global__ __launch_bounds__(NTHREADS) void wmse_reduce(
    const float* __restrict__ partial, float* __restrict__ out, float inv_n)
{
    __shared__ float s_red[NTHREADS / 64];
    float acc = 0.f;
    #pragma unroll
    for (int k = 0; k < NBLOCKS / NTHREADS; ++k)
        acc += partial[threadIdx.x + k * NTHREADS];

    #pragma unroll
    for (int off = 32; off > 0; off >>= 1)
        acc += __shfl_down(acc, off, 64);

    const int lane = threadIdx.x & 63;
    const int wave = threadIdx.x >> 6;
    if (lane == 0) s_red[wave] = acc;
    __syncthreads();
    if (threadIdx.x == 0) {
        float s = 0.f;
        #pragma unroll
        for (int w = 0; w < NTHREADS / 64; ++w) s += s_red[w];
        *out = s * inv_n;
    }
}

// Fallback (workspace too small): atomic single-kernel version.
__global__ __launch_bounds__(NTHREADS) void wmse_fused_atomic(
    const float* __restrict__ x,
    const float* __restrict__ y,
    const float* __restrict__ wt,
    float* __restrict__ out, int n, float inv_n)
{
    __shared__ float s_wt[NUM_LEVELS];
    __shared__ float s_red[NTHREADS / 64];

    for (int i = threadIdx.x; i < NUM_LEVELS; i += NTHREADS) s_wt[i] = wt[i];
    __syncthreads();

    const f32x4* __restrict__ x4 = (const f32x4*)x;
    const f32x4* __restrict__ y4 = (const f32x4*)y;
    const int n4 = n >> 2;
    const int stride = NBLOCKS * NTHREADS;
    const int base = blockIdx.x * NTHREADS + threadIdx.x;

    float a0 = 0.f, a1 = 0.f;
    for (int i = base; i < n4; i += stride) {
        f32x4 xv = x4[i], yv = y4[i];
        GATHER_ACC(yv, xv);
    }
    float acc = a0 + a1;

    #pragma unroll
    for (int off = 32; off > 0; off >>= 1)
        acc += __shfl_down(acc, off, 64);

    const int lane = threadIdx.x & 63;
    const int wave = threadIdx.x >> 6;
    if (lane == 0) s_red[wave] = acc;
    __syncthreads();
    if (threadIdx.x == 0) {
        float s = 0.f;
        #pragma unroll
        for (int w = 0; w < NTHREADS / 64; ++w) s += s_red[w];
        atomicAdd(out, s * inv_n);
    }
}

extern "C" void kernel_launch(void* const* d_in, const int* in_sizes, int n_in,
                              void* d_out, int out_size, void* d_ws, size_t ws_size,
                              hipStream_t stream) {
    const float* x  = (const float*)d_in[0];
    const float* y  = (const float*)d_in[1];
    const float* wt = (const float*)d_in[2];
    float* out = (float*)d_out;
    const int n = in_sizes[0];
    const float inv_n = 1.0f / (float)n;

    if (d_ws && ws_size >= NBLOCKS * sizeof(float)) {
        float* partial = (float*)d_ws;
        wmse_partial<<<NBLOCKS, NTHREADS, 0, stream>>>(x, y, wt, partial, n);
        wmse_reduce<<<1, NTHREADS, 0, stream>>>(partial, out, inv_n);
    } else {
        hipMemsetAsync(out, 0, sizeof(float), stream);
        wmse_fused_atomic<<<NBLOCKS, NTHREADS, 0, stream>>>(x, y, wt, out, n, inv_n);
    }
}

// Round 8
// 140.457 us; speedup vs baseline: 1.0195x; 1.0195x over previous
//
#include <hip/hip_runtime.h>

#define NBLOCKS 2048
#define NTHREADS 256
#define VPT 8                // float4s per array per thread; n4 == NBLOCKS*NTHREADS*VPT
#define OUTER 4              // steps of 2 float4s each
#define NUM_LEVELS 101

typedef float f32x4 __attribute__((ext_vector_type(4)));

// Pass-through pin (NO memory clobber): forces the s_waitcnt for these values
// here, while independent later nt-loads are free to hoist above -> rolling
// counted-vmcnt pipeline. Rounds 4/6 verified this form materializes;
// deeper/wider variants either collapse (rounds 1-3) or cross the 64-VGPR
// occupancy cliff (round 7, STEP=4: kernel 34.7 -> ~40 us).
#define PIN4(v) asm volatile("" : "+v"((v)[0]), "+v"((v)[1]), "+v"((v)[2]), "+v"((v)[3]))

#define GATHER_ACC(yv, xv)                                   \
    do {                                                     \
        float w0 = s_wt[__float2int_rn((yv)[0] * 100.f)];    \
        float w1 = s_wt[__float2int_rn((yv)[1] * 100.f)];    \
        float w2 = s_wt[__float2int_rn((yv)[2] * 100.f)];    \
        float w3 = s_wt[__float2int_rn((yv)[3] * 100.f)];    \
        float d0 = (xv)[0] - (yv)[0], d1 = (xv)[1] - (yv)[1];\
        float d2 = (xv)[2] - (yv)[2], d3 = (xv)[3] - (yv)[3];\
        a0 += d0 * d0 * w0 + d2 * d2 * w2;                   \
        a1 += d1 * d1 * w1 + d3 * d3 * w3;                   \
    } while (0)

// Stage 1: weighted-SSE partial sums, one float per block (plain store).
// nt loads (round 5: removed the L3/L2-allocation pacer; both arrays stream
// from HBM). Round-6 configuration: 2x float4 per array per step + 1-deep
// rolling PIN prefetch = best measured (kernel ~34.7 us, 3.86 TB/s read-only,
// the highest read rate measured on this box; copy read-stream = 3.15 TB/s,
// write-only fills = 6.6 TB/s). Depth/width/placement sweeps beyond this
// point are all null or regressions -> read-service ceiling.
__global__ __launch_bounds__(NTHREADS) void wmse_partial(
    const float* __restrict__ x,
    const float* __restrict__ y,
    const float* __restrict__ wt,
    float* __restrict__ partial, int n)
{
    __shared__ float s_wt[NUM_LEVELS];
    __shared__ float s_red[NTHREADS / 64];

    const f32x4* __restrict__ x4 = (const f32x4*)x;
    const f32x4* __restrict__ y4 = (const f32x4*)y;
    const int n4 = n >> 2;

    float acc = 0.f;

    if (n4 == NBLOCKS * NTHREADS * VPT) {
        if (threadIdx.x < NUM_LEVELS) s_wt[threadIdx.x] = wt[threadIdx.x];
        __syncthreads();

        const int i0 = blockIdx.x * (NTHREADS * VPT) + threadIdx.x;

        // preload step 0 (4 nt loads = 64 B/lane in flight)
        f32x4 yc0 = __builtin_nontemporal_load(y4 + i0);
        f32x4 yc1 = __builtin_nontemporal_load(y4 + i0 + NTHREADS);
        f32x4 xc0 = __builtin_nontemporal_load(x4 + i0);
        f32x4 xc1 = __builtin_nontemporal_load(x4 + i0 + NTHREADS);

        float a0 = 0.f, a1 = 0.f;
        #pragma unroll
        for (int k = 0; k < OUTER; ++k) {
            f32x4 yn0, yn1, xn0, xn1;
            if (k < OUTER - 1) {
                const int in = i0 + (k + 1) * (2 * NTHREADS);
                yn0 = __builtin_nontemporal_load(y4 + in);
                yn1 = __builtin_nontemporal_load(y4 + in + NTHREADS);
                xn0 = __builtin_nontemporal_load(x4 + in);
                xn1 = __builtin_nontemporal_load(x4 + in + NTHREADS);
            }
            // waits for CURRENT land here; next-step loads stay in flight
            PIN4(yc0); PIN4(yc1); PIN4(xc0); PIN4(xc1);
            GATHER_ACC(yc0, xc0);
            GATHER_ACC(yc1, xc1);
            if (k < OUTER - 1) {
                yc0 = yn0; yc1 = yn1; xc0 = xn0; xc1 = xn1;
            }
        }
        acc = a0 + a1;
    } else {
        // Generic fallback path (grid-stride, normal loads).
        for (int i = threadIdx.x; i < NUM_LEVELS; i += NTHREADS) s_wt[i] = wt[i];
        __syncthreads();
        const int stride = NBLOCKS * NTHREADS;
        float a0 = 0.f, a1 = 0.f;
        for (int i = blockIdx.x * NTHREADS + threadIdx.x; i < n4; i += stride) {
            f32x4 xv = x4[i], yv = y4[i];
            GATHER_ACC(yv, xv);
        }
        acc = a0 + a1;
    }

    // wave-64 shuffle reduction
    #pragma unroll
    for (int off = 32; off > 0; off >>= 1)
        acc += __shfl_down(acc, off, 64);

    const int lane = threadIdx.x & 63;
    const int wave = threadIdx.x >> 6;
    if (lane == 0) s_red[wave] = acc;
    __syncthreads();
    if (threadIdx.x == 0) {
        float s = 0.f;
        #pragma unroll
        for (int w = 0; w < NTHREADS / 64; ++w) s += s_red[w];
        partial[blockIdx.x] = s;   // plain store, no atomic
    }
}

// Stage 2: one block folds the partials and writes the final mean.
// Overwrites the poisoned output directly -> no memset node needed.
__global__ __launch_bounds__(NTHREADS) void wmse_reduce(
    const float* __restrict__ partial, float* __restrict__ out, float inv_n)
{
    __shared__ float s_red[NTHREADS / 64];
    float acc = 0.f;
    #pragma unroll
    for (int k = 0; k < NBLOCKS / NTHREADS; ++k)
        acc += partial[threadIdx.x + k * NTHREADS];

    #pragma unroll
    for (int off = 32; off > 0; off >>= 1)
        acc += __shfl_down(acc, off, 64);

    const int lane = threadIdx.x & 63;
    const int wave = threadIdx.x >> 6;
    if (lane == 0) s_red[wave] = acc;
    __syncthreads();
    if (threadIdx.x == 0) {
        float s = 0.f;
        #pragma unroll
        for (int w = 0; w < NTHREADS / 64; ++w) s += s_red[w];
        *out = s * inv_n;
    }
}

// Fallback (workspace too small): atomic single-kernel version.
__global__ __launch_bounds__(NTHREADS) void wmse_fused_atomic(
    const float* __restrict__ x,
    const float* __restrict__ y,
    const float* __restrict__ wt,
    float* __restrict__ out, int n, float inv_n)
{
    __shared__ float s_wt[NUM_LEVELS];
    __shared__ float s_red[NTHREADS / 64];

    for (int i = threadIdx.x; i < NUM_LEVELS; i += NTHREADS) s_wt[i] = wt[i];
    __syncthreads();

    const f32x4* __restrict__ x4 = (const f32x4*)x;
    const f32x4* __restrict__ y4 = (const f32x4*)y;
    const int n4 = n >> 2;
    const int stride = NBLOCKS * NTHREADS;
    const int base = blockIdx.x * NTHREADS + threadIdx.x;

    float a0 = 0.f, a1 = 0.f;
    for (int i = base; i < n4; i += stride) {
        f32x4 xv = x4[i], yv = y4[i];
        GATHER_ACC(yv, xv);
    }
    float acc = a0 + a1;

    #pragma unroll
    for (int off = 32; off > 0; off >>= 1)
        acc += __shfl_down(acc, off, 64);

    const int lane = threadIdx.x & 63;
    const int wave = threadIdx.x >> 6;
    if (lane == 0) s_red[wave] = acc;
    __syncthreads();
    if (threadIdx.x == 0) {
        float s = 0.f;
        #pragma unroll
        for (int w = 0; w < NTHREADS / 64; ++w) s += s_red[w];
        atomicAdd(out, s * inv_n);
    }
}

extern "C" void kernel_launch(void* const* d_in, const int* in_sizes, int n_in,
                              void* d_out, int out_size, void* d_ws, size_t ws_size,
                              hipStream_t stream) {
    const float* x  = (const float*)d_in[0];
    const float* y  = (const float*)d_in[1];
    const float* wt = (const float*)d_in[2];
    float* out = (float*)d_out;
    const int n = in_sizes[0];
    const float inv_n = 1.0f / (float)n;

    if (d_ws && ws_size >= NBLOCKS * sizeof(float)) {
        float* partial = (float*)d_ws;
        wmse_partial<<<NBLOCKS, NTHREADS, 0, stream>>>(x, y, wt, partial, n);
        wmse_reduce<<<1, NTHREADS, 0, stream>>>(partial, out, inv_n);
    } else {
        hipMemsetAsync(out, 0, sizeof(float), stream);
        wmse_fused_atomic<<<NBLOCKS, NTHREADS, 0, stream>>>(x, y, wt, out, n, inv_n);
    }
}

// Round 9
// 139.810 us; speedup vs baseline: 1.0242x; 1.0046x over previous
//
#include <hip/hip_runtime.h>

#define NBLOCKS 2048
#define NTHREADS 256
#define VPT 8                // float4s per array per thread; n4 == NBLOCKS*NTHREADS*VPT
#define OUTER 4              // steps of 2 float4s each
#define HBLOCKS 1472         // blocks 0..1471: nt->HBM path (71.9% of bytes);
                             // blocks 1472..2047: cached->L3 path (28.1%)
#define NUM_LEVELS 101

typedef float f32x4 __attribute__((ext_vector_type(4)));

// Pass-through pin (NO memory clobber): forces the s_waitcnt for these values
// here, while independent later loads hoist above -> rolling counted-vmcnt
// pipeline (rounds 4/6 verified this survives the scheduler; deeper/wider
// variants collapse or cross the 64-VGPR cliff).
#define PIN4(v) asm volatile("" : "+v"((v)[0]), "+v"((v)[1]), "+v"((v)[2]), "+v"((v)[3]))

#define GATHER_ACC(yv, xv)                                   \
    do {                                                     \
        float w0 = s_wt[__float2int_rn((yv)[0] * 100.f)];    \
        float w1 = s_wt[__float2int_rn((yv)[1] * 100.f)];    \
        float w2 = s_wt[__float2int_rn((yv)[2] * 100.f)];    \
        float w3 = s_wt[__float2int_rn((yv)[3] * 100.f)];    \
        float d0 = (xv)[0] - (yv)[0], d1 = (xv)[1] - (yv)[1];\
        float d2 = (xv)[2] - (yv)[2], d3 = (xv)[3] - (yv)[3];\
        a0 += d0 * d0 * w0 + d2 * d2 * w2;                   \
        a1 += d1 * d1 * w1 + d3 * d3 * w3;                   \
    } while (0)

template <bool NT>
__device__ __forceinline__ f32x4 ldv(const f32x4* __restrict__ p) {
    if constexpr (NT) return __builtin_nontemporal_load(p);
    else              return *p;
}

// Round-6 inner loop, path-templated. NT blocks stream from HBM (no cache
// retention); cached blocks' fixed 37.6-MB range stays L3-resident across
// launches (rounds 0-4: 64 MB demonstrably survived the harness fills).
// Range-decoupling means no wave couples the two service paths.
template <bool NT>
__device__ __forceinline__ float fastpath(const f32x4* __restrict__ x4,
                                          const f32x4* __restrict__ y4,
                                          const float* s_wt, int i0) {
    f32x4 yc0 = ldv<NT>(y4 + i0);
    f32x4 yc1 = ldv<NT>(y4 + i0 + NTHREADS);
    f32x4 xc0 = ldv<NT>(x4 + i0);
    f32x4 xc1 = ldv<NT>(x4 + i0 + NTHREADS);

    float a0 = 0.f, a1 = 0.f;
    #pragma unroll
    for (int k = 0; k < OUTER; ++k) {
        f32x4 yn0, yn1, xn0, xn1;
        if (k < OUTER - 1) {
            const int in = i0 + (k + 1) * (2 * NTHREADS);
            yn0 = ldv<NT>(y4 + in);
            yn1 = ldv<NT>(y4 + in + NTHREADS);
            xn0 = ldv<NT>(x4 + in);
            xn1 = ldv<NT>(x4 + in + NTHREADS);
        }
        // waits for CURRENT land here; next-step loads stay in flight
        PIN4(yc0); PIN4(yc1); PIN4(xc0); PIN4(xc1);
        GATHER_ACC(yc0, xc0);
        GATHER_ACC(yc1, xc1);
        if (k < OUTER - 1) {
            yc0 = yn0; yc1 = yn1; xc0 = xn0; xc1 = xn1;
        }
    }
    return a0 + a1;
}

// Stage 1: weighted-SSE partial sums, one float per block (plain store).
// Hybrid path-split: rounds 0-4 showed L3-hit and HBM streams each ran at
// 1.5 TB/s when coupled 1:1 within waves (total 3.0 < the 3.86 nt-only cap),
// i.e. the shared request path was NOT saturated -- the paths may add when
// decoupled by range. 71.9% nt (3.86 TB/s) || 28.1% cached (L3, ~1.5 TB/s)
// -> ~25 us if additive; flat 35 us + FETCH drop -> shared-path cap proven.
__global__ __launch_bounds__(NTHREADS) void wmse_partial(
    const float* __restrict__ x,
    const float* __restrict__ y,
    const float* __restrict__ wt,
    float* __restrict__ partial, int n)
{
    __shared__ float s_wt[NUM_LEVELS];
    __shared__ float s_red[NTHREADS / 64];

    const f32x4* __restrict__ x4 = (const f32x4*)x;
    const f32x4* __restrict__ y4 = (const f32x4*)y;
    const int n4 = n >> 2;

    float acc = 0.f;

    if (n4 == NBLOCKS * NTHREADS * VPT) {
        if (threadIdx.x < NUM_LEVELS) s_wt[threadIdx.x] = wt[threadIdx.x];
        __syncthreads();

        const int i0 = blockIdx.x * (NTHREADS * VPT) + threadIdx.x;
        acc = (blockIdx.x < HBLOCKS)
                  ? fastpath<true >(x4, y4, s_wt, i0)
                  : fastpath<false>(x4, y4, s_wt, i0);
    } else {
        // Generic fallback path (grid-stride, normal loads).
        for (int i = threadIdx.x; i < NUM_LEVELS; i += NTHREADS) s_wt[i] = wt[i];
        __syncthreads();
        const int stride = NBLOCKS * NTHREADS;
        float a0 = 0.f, a1 = 0.f;
        for (int i = blockIdx.x * NTHREADS + threadIdx.x; i < n4; i += stride) {
            f32x4 xv = x4[i], yv = y4[i];
            GATHER_ACC(yv, xv);
        }
        acc = a0 + a1;
    }

    // wave-64 shuffle reduction
    #pragma unroll
    for (int off = 32; off > 0; off >>= 1)
        acc += __shfl_down(acc, off, 64);

    const int lane = threadIdx.x & 63;
    const int wave = threadIdx.x >> 6;
    if (lane == 0) s_red[wave] = acc;
    __syncthreads();
    if (threadIdx.x == 0) {
        float s = 0.f;
        #pragma unroll
        for (int w = 0; w < NTHREADS / 64; ++w) s += s_red[w];
        partial[blockIdx.x] = s;   // plain store, no atomic
    }
}

// Stage 2: one block folds the partials and writes the final mean.
// Overwrites the poisoned output directly -> no memset node needed.
__global__ __launch_bounds__(NTHREADS) void wmse_reduce(
    const float* __restrict__ partial, float* __restrict__ out, float inv_n)
{
    __shared__ float s_red[NTHREADS / 64];
    float acc = 0.f;
    #pragma unroll
    for (int k = 0; k < NBLOCKS / NTHREADS; ++k)
        acc += partial[threadIdx.x + k * NTHREADS];

    #pragma unroll
    for (int off = 32; off > 0; off >>= 1)
        acc += __shfl_down(acc, off, 64);

    const int lane = threadIdx.x & 63;
    const int wave = threadIdx.x >> 6;
    if (lane == 0) s_red[wave] = acc;
    __syncthreads();
    if (threadIdx.x == 0) {
        float s = 0.f;
        #pragma unroll
        for (int w = 0; w < NTHREADS / 64; ++w) s += s_red[w];
        *out = s * inv_n;
    }
}

// Fallback (workspace too small): atomic single-kernel version.
__global__ __launch_bounds__(NTHREADS) void wmse_fused_atomic(
    const float* __restrict__ x,
    const float* __restrict__ y,
    const float* __restrict__ wt,
    float* __restrict__ out, int n, float inv_n)
{
    __shared__ float s_wt[NUM_LEVELS];
    __shared__ float s_red[NTHREADS / 64];

    for (int i = threadIdx.x; i < NUM_LEVELS; i += NTHREADS) s_wt[i] = wt[i];
    __syncthreads();

    const f32x4* __restrict__ x4 = (const f32x4*)x;
    const f32x4* __restrict__ y4 = (const f32x4*)y;
    const int n4 = n >> 2;
    const int stride = NBLOCKS * NTHREADS;
    const int base = blockIdx.x * NTHREADS + threadIdx.x;

    float a0 = 0.f, a1 = 0.f;
    for (int i = base; i < n4; i += stride) {
        f32x4 xv = x4[i], yv = y4[i];
        GATHER_ACC(yv, xv);
    }
    float acc = a0 + a1;

    #pragma unroll
    for (int off = 32; off > 0; off >>= 1)
        acc += __shfl_down(acc, off, 64);

    const int lane = threadIdx.x & 63;
    const int wave = threadIdx.x >> 6;
    if (lane == 0) s_red[wave] = acc;
    __syncthreads();
    if (threadIdx.x == 0) {
        float s = 0.f;
        #pragma unroll
        for (int w = 0; w < NTHREADS / 64; ++w) s += s_red[w];
        atomicAdd(out, s * inv_n);
    }
}

extern "C" void kernel_launch(void* const* d_in, const int* in_sizes, int n_in,
                              void* d_out, int out_size, void* d_ws, size_t ws_size,
                              hipStream_t stream) {
    const float* x  = (const float*)d_in[0];
    const float* y  = (const float*)d_in[1];
    const float* wt = (const float*)d_in[2];
    float* out = (float*)d_out;
    const int n = in_sizes[0];
    const float inv_n = 1.0f / (float)n;

    if (d_ws && ws_size >= NBLOCKS * sizeof(float)) {
        float* partial = (float*)d_ws;
        wmse_partial<<<NBLOCKS, NTHREADS, 0, stream>>>(x, y, wt, partial, n);
        wmse_reduce<<<1, NTHREADS, 0, stream>>>(partial, out, inv_n);
    } else {
        hipMemsetAsync(out, 0, sizeof(float), stream);
        wmse_fused_atomic<<<NBLOCKS, NTHREADS, 0, stream>>>(x, y, wt, out, n, inv_n);
    }
}